// Round 1
// 632.407 us; speedup vs baseline: 1.1055x; 1.1055x over previous
//
#include <hip/hip_runtime.h>
#include <hip/hip_bf16.h>

// PointerNetwork: B=4096, L=10, IN=8, H=512, W=512. fp32 in/out, ws=256MiB.
// log_softmax over size-1 axes => hi==he==0. Surviving compute:
//   enc GRU, ew3 = h_enc @ w3^T, dec GRU, a4 = h_dec @ w4^T,
//   out_seq = tanh(ew3+a4)@v2, out_ori = h_dec @ wori[:,H:2H]^T + bori.
// Round 7: gru_fused rebuilt as BK=64 double-buffered counted-vmcnt pipeline
// (T3/T4-lite) + XOR-swizzled LDS (T2, both-sides w/ global_load_lds) +
// setprio (T5). out_seq_all: f32 LDS staging, prescaled-by-LOG2E2 inputs
// (applied in gemm epilogue), registerized -2*v2 with sum-extraction
// (tanh = 1 - 2*rcp(exp2+1)). Decoder xg stored bf16.

#define B_   4096
#define L_   10
#define IN_  8
#define H_   512
#define H3_  1536
#define W_   512
#define ORI_BASE (B_ * L_ * L_)   // 409600

typedef __attribute__((ext_vector_type(8))) short s8v;
typedef __attribute__((ext_vector_type(4))) float f4v;

#define LOG2E  1.4426950408889634f
#define LOG2E2 2.8853900817779268f

__device__ __forceinline__ float sig_fast(float x) {
  float e = __builtin_amdgcn_exp2f(-x * LOG2E);
  return __builtin_amdgcn_rcpf(1.f + e);
}
__device__ __forceinline__ float tanh_fast(float x) {
  float e = __builtin_amdgcn_exp2f(x * LOG2E2);
  return 1.f - 2.f * __builtin_amdgcn_rcpf(e + 1.f);
}
__device__ __forceinline__ short f2bf(float f) {
  __hip_bfloat16 h = __float2bfloat16(f);
  return __builtin_bit_cast(short, h);
}
__device__ __forceinline__ float bf2f(short s) {
  __hip_bfloat16 h = __builtin_bit_cast(__hip_bfloat16, s);
  return __bfloat162float(h);
}
__device__ __forceinline__ void stc(float* p, float v) { *p = v; }
__device__ __forceinline__ void stc(short* p, float v) { *p = f2bf(v); }

__global__ __launch_bounds__(256) void f2bf_k(const float* __restrict__ src,
                                              short* __restrict__ dst, int n)
{
  int i = blockIdx.x * 256 + threadIdx.x;
  if (i < n) dst[i] = f2bf(src[i]);
}

// Fold embedding into encoder input weight. One wave per g-row (1536 waves).
__global__ __launch_bounds__(256) void build_wc(
    const float* __restrict__ enc_wih, const float* __restrict__ emb_w,
    const float* __restrict__ emb_b, const float* __restrict__ enc_bih,
    float* __restrict__ Wc, float* __restrict__ bc)
{
  __shared__ float se[H_ * IN_];   // 16 KB
  __shared__ float sb[H_];         // 2 KB
  const int tid = threadIdx.x;
  for (int i = tid; i < H_ * IN_; i += 256) se[i] = emb_w[i];
  for (int i = tid; i < H_; i += 256) sb[i] = emb_b[i];
  __syncthreads();
  int g = (blockIdx.x * 256 + tid) >> 6;
  int lane = tid & 63;
  const float* wr = enc_wih + (long)g * H_ + lane * 8;
  float w8[8];
#pragma unroll
  for (int j = 0; j < 8; ++j) w8[j] = wr[j];
  float acc[9] = {};
#pragma unroll
  for (int kk = 0; kk < 8; ++kk) {
    int k = lane * 8 + kk;
#pragma unroll
    for (int j = 0; j < 8; ++j) acc[j] += w8[kk] * se[k * IN_ + j];
    acc[8] += w8[kk] * sb[k];
  }
#pragma unroll
  for (int j = 0; j < 9; ++j)
#pragma unroll
    for (int off = 32; off; off >>= 1) acc[j] += __shfl_down(acc[j], off, 64);
  if (lane == 0) {
#pragma unroll
    for (int j = 0; j < 8; ++j) Wc[g * IN_ + j] = acc[j];
    bc[g] = acc[8] + enc_bih[g];
  }
}

// bf16 MFMA GEMM: C[M,N] = (A[M,K] @ B[N,K]^T (+bias)) * scale. 128x128, BK=32.
template <typename CT>
__global__ __launch_bounds__(256) void gemm_bf16(
    const short* __restrict__ A, long lda,
    const short* __restrict__ Bw, long ldb,
    const float* __restrict__ bias,
    CT* __restrict__ C, long ldc, int K, float scale)
{
  __shared__ short As[128 * 32];
  __shared__ short Bs[128 * 32];
  const int tid = threadIdx.x;
  const long row0 = (long)blockIdx.y * 128;
  const long col0 = (long)blockIdx.x * 128;
  const int wave = tid >> 6, lane = tid & 63;
  const int wm = (wave & 1) * 64, wn = (wave >> 1) * 64;
  const int r16 = lane & 15, quad = lane >> 4;
  f4v acc[4][4] = {};

  for (int k0 = 0; k0 < K; k0 += 32) {
#pragma unroll
    for (int r = 0; r < 2; ++r) {
      int idx = r * 256 + tid;
      int m = idx >> 2;
      int k8 = (idx & 3) * 8;
      __builtin_amdgcn_global_load_lds(
          (const __attribute__((address_space(1))) void*)(A + (row0 + m) * lda + k0 + k8),
          (__attribute__((address_space(3))) void*)(As + idx * 8), 16, 0, 0);
      __builtin_amdgcn_global_load_lds(
          (const __attribute__((address_space(1))) void*)(Bw + (col0 + m) * ldb + k0 + k8),
          (__attribute__((address_space(3))) void*)(Bs + idx * 8), 16, 0, 0);
    }
    __syncthreads();
    s8v af[4], bf[4];
#pragma unroll
    for (int i = 0; i < 4; ++i)
      af[i] = *(const s8v*)&As[(wm + i * 16 + r16) * 32 + quad * 8];
#pragma unroll
    for (int j = 0; j < 4; ++j)
      bf[j] = *(const s8v*)&Bs[(wn + j * 16 + r16) * 32 + quad * 8];
#pragma unroll
    for (int i = 0; i < 4; ++i)
#pragma unroll
      for (int j = 0; j < 4; ++j)
        acc[i][j] = __builtin_amdgcn_mfma_f32_16x16x32_bf16(af[i], bf[j], acc[i][j], 0, 0, 0);
    __syncthreads();
  }

#pragma unroll
  for (int i = 0; i < 4; ++i) {
    long rbase = row0 + wm + i * 16 + quad * 4;
#pragma unroll
    for (int j = 0; j < 4; ++j) {
      long c = col0 + wn + j * 16 + r16;
      float bv = bias ? bias[c] : 0.f;
#pragma unroll
      for (int rg = 0; rg < 4; ++rg)
        stc(&C[(rbase + rg) * ldc + c], (acc[i][j][rg] + bv) * scale);
    }
  }
}

// ---- Fused GRU step. Tile: 64 rows x 64 cols x 3 gates. Grid (8,64)=512
// blocks (2/CU, whole grid resident). BK=64, double-buffered LDS (64KB),
// counted vmcnt(8) prefetch pipeline, XOR-swizzled LDS chunks (16B grain:
// chunk c8 <-> c8 ^ (row&7); applied on global SOURCE addr at stage and on
// ds_read addr -- rule #21 both-sides with global_load_lds linear dest).
template <bool ENC>
__global__ __launch_bounds__(256) void gru_fused(
    const short* __restrict__ Aprev,  // (B,H) bf16 h_{t-1}
    const short* __restrict__ Whh,    // (3H,H) bf16
    const float* __restrict__ bhh,    // (3H)
    const short* __restrict__ xg,     // (B,3H) bf16 (decoder)
    const float* __restrict__ items_t,// encoder: &items[0][t][0], row stride 80
    const float* __restrict__ Wc,     // (3H,8)
    const float* __restrict__ bc,     // (3H)
    float* __restrict__ h,            // (B,H) fp32 master (in/out)
    short* __restrict__ hout)         // (B,H) bf16 history slice
{
  __shared__ short As[2][64 * 64];    // 16 KB
  __shared__ short Bs[2][192 * 64];   // 48 KB
  const int tid = threadIdx.x;
  const long row0 = (long)blockIdx.y * 64;
  const int col0 = blockIdx.x * 64;
  const int wave = tid >> 6, lane = tid & 63;
  const int r16 = lane & 15, quad = lane >> 4;
  const int sw = r16 & 7;

  f4v acc[3][4] = {};   // [gate][frag-row]

  auto stage = [&](int buf, int k0) {
#pragma unroll
    for (int r = 0; r < 2; ++r) {             // A: 64x64 = 512 chunks
      int idx = r * 256 + tid;
      int m = idx >> 3, c8 = idx & 7;
      int src = c8 ^ (m & 7);
      __builtin_amdgcn_global_load_lds(
          (const __attribute__((address_space(1))) void*)(Aprev + (row0 + m) * H_ + k0 + src * 8),
          (__attribute__((address_space(3))) void*)(&As[buf][idx * 8]), 16, 0, 0);
    }
#pragma unroll
    for (int r = 0; r < 6; ++r) {             // B: 192x64 = 1536 chunks
      int idx = r * 256 + tid;
      int m = idx >> 3, c8 = idx & 7;
      int src = c8 ^ (m & 7);
      int g = m >> 6, cc = m & 63;
      __builtin_amdgcn_global_load_lds(
          (const __attribute__((address_space(1))) void*)(Whh + ((long)g * H_ + col0 + cc) * H_ + k0 + src * 8),
          (__attribute__((address_space(3))) void*)(&Bs[buf][idx * 8]), 16, 0, 0);
    }
  };

  stage(0, 0);
  int cur = 0;
  for (int k = 0; k < 8; ++k) {
    if (k < 7) {
      stage(cur ^ 1, (k + 1) * 64);
      asm volatile("s_waitcnt vmcnt(8)" ::: "memory");   // cur's 8 loads done
    } else {
      asm volatile("s_waitcnt vmcnt(0)" ::: "memory");
    }
    __builtin_amdgcn_s_barrier();
    s8v af[4][2], bf[3][2];
#pragma unroll
    for (int i = 0; i < 4; ++i)
#pragma unroll
      for (int hh = 0; hh < 2; ++hh)
        af[i][hh] = *(const s8v*)&As[cur][(i * 16 + r16) * 64 + ((hh * 4 + quad) ^ sw) * 8];
#pragma unroll
    for (int g = 0; g < 3; ++g)
#pragma unroll
      for (int hh = 0; hh < 2; ++hh)
        bf[g][hh] = *(const s8v*)&Bs[cur][(g * 64 + wave * 16 + r16) * 64 + ((hh * 4 + quad) ^ sw) * 8];
    __builtin_amdgcn_s_setprio(1);
#pragma unroll
    for (int hh = 0; hh < 2; ++hh)
#pragma unroll
      for (int g = 0; g < 3; ++g)
#pragma unroll
        for (int i = 0; i < 4; ++i)
          acc[g][i] = __builtin_amdgcn_mfma_f32_16x16x32_bf16(af[i][hh], bf[g][hh], acc[g][i], 0, 0, 0);
    __builtin_amdgcn_s_setprio(0);
    __builtin_amdgcn_s_barrier();
    cur ^= 1;
  }

  // Column owned by this thread (C/D layout: col=lane&15, row=quad*4+reg).
  const int col = col0 + wave * 16 + r16;
  float wc[3][8], bcv[3];
  if (ENC) {
#pragma unroll
    for (int g = 0; g < 3; ++g) {
      const float* wr = Wc + ((long)g * H_ + col) * IN_;
#pragma unroll
      for (int j = 0; j < 8; ++j) wc[g][j] = wr[j];
      bcv[g] = bc[g * H_ + col];
    }
    // stage items rows into LDS (reuse As[0]): 64 rows x 8 fp32
    float* itemS = (float*)As;
    int i2 = tid * 2;
    int m = i2 >> 3, j = i2 & 7;
    itemS[i2] = items_t[(row0 + m) * (L_ * IN_) + j];
    itemS[i2 + 1] = items_t[(row0 + m) * (L_ * IN_) + j + 1];
    __syncthreads();
  }
  float bhr = bhh[col], bhz = bhh[col + H_], bhn = bhh[col + 2 * H_];

#pragma unroll
  for (int i = 0; i < 4; ++i) {
#pragma unroll
    for (int rg = 0; rg < 4; ++rg) {
      int rl = i * 16 + quad * 4 + rg;
      long row = row0 + rl;
      float xr, xz, xn;
      if (ENC) {
        const float* it = (const float*)As + rl * 8;
        xr = bcv[0]; xz = bcv[1]; xn = bcv[2];
#pragma unroll
        for (int j = 0; j < 8; ++j) {
          float iv = it[j];
          xr += iv * wc[0][j];
          xz += iv * wc[1][j];
          xn += iv * wc[2][j];
        }
      } else {
        long gx = row * H3_ + col;
        xr = bf2f(xg[gx]); xz = bf2f(xg[gx + H_]); xn = bf2f(xg[gx + 2 * H_]);
      }
      float r = sig_fast(xr + acc[0][i][rg] + bhr);
      float z = sig_fast(xz + acc[1][i][rg] + bhz);
      float n = tanh_fast(xn + r * (acc[2][i][rg] + bhn));
      long hi = row * H_ + col;
      float hv = (1.f - z) * n + z * h[hi];
      h[hi] = hv;
      hout[hi] = f2bf(hv);
    }
  }
}

// ---- batched out_seq: one block per b. ew3/a4 arrive pre-scaled by LOG2E2,
// staged as f32 in LDS. tanh(x) = 1 - 2*rcp(exp2(x*LOG2E2)+1); fold the "1"
// into svtot = sum(v2) and the -2 into svp[] registers.
__global__ __launch_bounds__(256) void out_seq_all(
    const short* __restrict__ ew3,   // (Lenc, B, W) bf16, prescaled
    const short* __restrict__ a4,    // (Ldec, B, W) bf16, prescaled
    const float* __restrict__ v2,
    float* __restrict__ out)
{
  __shared__ float se[L_ * W_];   // 20 KB
  __shared__ float sa[L_ * W_];   // 20 KB
  const int b = blockIdx.x;
  const int tid = threadIdx.x;
  for (int i = tid; i < L_ * W_ / 8; i += 256) {
    int l = i >> 6, c = i & 63;
    s8v ev = *(const s8v*)(ew3 + ((long)l * B_ + b) * W_ + c * 8);
    s8v av = *(const s8v*)(a4 + ((long)l * B_ + b) * W_ + c * 8);
    f4v e0, e1, a0, a1;
#pragma unroll
    for (int j = 0; j < 4; ++j) {
      e0[j] = bf2f(ev[j]); e1[j] = bf2f(ev[j + 4]);
      a0[j] = bf2f(av[j]); a1[j] = bf2f(av[j + 4]);
    }
    *(f4v*)(se + i * 8) = e0; *(f4v*)(se + i * 8 + 4) = e1;
    *(f4v*)(sa + i * 8) = a0; *(f4v*)(sa + i * 8 + 4) = a1;
  }
  const int wave = tid >> 6, lane = tid & 63;
  float svp[8], svtot = 0.f;
#pragma unroll
  for (int j = 0; j < 8; ++j) {
    float v = v2[lane * 8 + j];
    svp[j] = -2.f * v;
    svtot += v;
  }
#pragma unroll
  for (int off = 32; off; off >>= 1) svtot += __shfl_down(svtot, off, 64);
  __syncthreads();

#pragma unroll
  for (int pp = 0; pp < 25; ++pp) {
    int p = wave * 25 + pp;       // 100 (t,l) pairs over 4 waves
    int t = p / L_, l = p - t * L_;
    const float* ep = se + l * W_ + lane * 8;
    const float* ap = sa + t * W_ + lane * 8;
    f4v e0 = *(const f4v*)ep, e1 = *(const f4v*)(ep + 4);
    f4v a0 = *(const f4v*)ap, a1 = *(const f4v*)(ap + 4);
    float acc = 0.f;
#pragma unroll
    for (int j = 0; j < 4; ++j) {
      float x0 = __builtin_amdgcn_exp2f(e0[j] + a0[j]);
      acc += svp[j] * __builtin_amdgcn_rcpf(x0 + 1.f);
      float x1 = __builtin_amdgcn_exp2f(e1[j] + a1[j]);
      acc += svp[j + 4] * __builtin_amdgcn_rcpf(x1 + 1.f);
    }
#pragma unroll
    for (int off = 32; off; off >>= 1) acc += __shfl_down(acc, off, 64);
    if (lane == 0) out[((long)b * L_ + t) * L_ + l] = svtot + acc;
  }
}

// ---- batched out_ori: one wave per (b,t). ----
__global__ __launch_bounds__(256) void out_ori_all(
    const short* __restrict__ dh,    // (Ldec, B, H) bf16
    const float* __restrict__ wori, const float* __restrict__ bori,
    float* __restrict__ out)
{
  int wid = (blockIdx.x * 256 + threadIdx.x) >> 6;   // b*L + t
  int lane = threadIdx.x & 63;
  int b = wid / L_, t = wid - b * L_;
  s8v hv = *(const s8v*)(dh + ((long)t * B_ + b) * H_ + lane * 8);
  float hf[8];
#pragma unroll
  for (int j = 0; j < 8; ++j) hf[j] = bf2f(hv[j]);
  float res[6];
#pragma unroll
  for (int o = 0; o < 6; ++o) {
    const float* wr = wori + (long)o * H3_ + H_ + lane * 8;
    float acc = 0.f;
#pragma unroll
    for (int j = 0; j < 8; ++j) acc += hf[j] * wr[j];
#pragma unroll
    for (int off = 32; off; off >>= 1) acc += __shfl_down(acc, off, 64);
    res[o] = acc;
  }
  if (lane == 0) {
    float* po = out + ORI_BASE + ((long)b * L_ + t) * 6;
#pragma unroll
    for (int o = 0; o < 6; ++o) po[o] = res[o] + bori[o];
  }
}

extern "C" void kernel_launch(void* const* d_in, const int* in_sizes, int n_in,
                              void* d_out, int out_size, void* d_ws, size_t ws_size,
                              hipStream_t stream)
{
  const float* items   = (const float*)d_in[0];
  const float* dec_in  = (const float*)d_in[1];
  const float* emb_w   = (const float*)d_in[2];
  const float* emb_b   = (const float*)d_in[3];
  const float* enc_wih = (const float*)d_in[4];
  const float* enc_whh = (const float*)d_in[5];
  const float* enc_bih = (const float*)d_in[6];
  const float* enc_bhh = (const float*)d_in[7];
  const float* dec_wih = (const float*)d_in[8];
  const float* dec_whh = (const float*)d_in[9];
  const float* dec_bih = (const float*)d_in[10];
  const float* dec_bhh = (const float*)d_in[11];
  const float* w3      = (const float*)d_in[14];
  const float* w4      = (const float*)d_in[15];
  const float* v2      = (const float*)d_in[20];
  const float* wori    = (const float*)d_in[23];
  const float* bori    = (const float*)d_in[24];
  float* out = (float*)d_out;

  char* ws = (char*)d_ws;
  size_t off = 0;
  auto alloc = [&](size_t bytes) { size_t o = off; off += (bytes + 255) & ~255UL; return o; };
  float* Wc       = (float*)(ws + alloc(H3_ * IN_ * 4));
  float* bc       = (float*)(ws + alloc(H3_ * 4));
  float* h        = (float*)(ws + alloc((size_t)B_ * H_ * 4));           // 8 MiB
  short* xgb      = (short*)(ws + alloc((size_t)B_ * H3_ * 2));          // 12 MiB
  short* enc_hist = (short*)(ws + alloc((size_t)11 * B_ * H_ * 2));      // 44 MiB
  short* dec_hist = (short*)(ws + alloc((size_t)L_ * B_ * H_ * 2));      // 40 MiB
  short* ew3      = (short*)(ws + alloc((size_t)L_ * B_ * W_ * 2));      // 40 MiB
  short* a4       = (short*)(ws + alloc((size_t)L_ * B_ * W_ * 2));      // 40 MiB
  short* whh_e    = (short*)(ws + alloc((size_t)H3_ * H_ * 2));
  short* whh_d    = (short*)(ws + alloc((size_t)H3_ * H_ * 2));
  short* wih_d    = (short*)(ws + alloc((size_t)H3_ * H_ * 2));
  short* w3b      = (short*)(ws + alloc((size_t)W_ * H_ * 2));
  short* w4b      = (short*)(ws + alloc((size_t)W_ * H_ * 2));
  short* decb     = (short*)(ws + alloc((size_t)B_ * H_ * 2));           // 4 MiB

  // ---- prep ----
  f2bf_k<<<(H3_ * H_ + 255) / 256, 256, 0, stream>>>(enc_whh, whh_e, H3_ * H_);
  f2bf_k<<<(H3_ * H_ + 255) / 256, 256, 0, stream>>>(dec_whh, whh_d, H3_ * H_);
  f2bf_k<<<(H3_ * H_ + 255) / 256, 256, 0, stream>>>(dec_wih, wih_d, H3_ * H_);
  f2bf_k<<<(W_ * H_ + 255) / 256, 256, 0, stream>>>(w3, w3b, W_ * H_);
  f2bf_k<<<(W_ * H_ + 255) / 256, 256, 0, stream>>>(w4, w4b, W_ * H_);
  f2bf_k<<<(B_ * H_ + 255) / 256, 256, 0, stream>>>(dec_in, decb, B_ * H_);
  build_wc<<<384, 256, 0, stream>>>(enc_wih, emb_w, emb_b, enc_bih, Wc, bc);

  hipMemsetAsync(h, 0, (size_t)B_ * H_ * 4, stream);             // h0 = 0
  hipMemsetAsync(enc_hist, 0, (size_t)B_ * H_ * 2, stream);      // slice 0 = 0

  // ---- Encoder recurrence: single fused kernel per step (xg inline) ----
  for (int t = 0; t < L_; ++t) {
    gru_fused<true><<<dim3(8, 64), 256, 0, stream>>>(
        enc_hist + (size_t)t * B_ * H_, whh_e, enc_bhh, nullptr,
        items + (size_t)t * IN_, Wc, bc, h,
        enc_hist + (size_t)(t + 1) * B_ * H_);
  }

  // xg_dec = dec_in @ dec_wih^T + dec_bih (fixed across decoder steps), bf16
  gemm_bf16<short><<<dim3(12, 32), 256, 0, stream>>>(
      decb, H_, wih_d, H_, dec_bih, xgb, H3_, H_, 1.f);

  // ---- Decoder recurrence ----
  for (int t = 0; t < L_; ++t) {
    const short* prev = (t == 0) ? enc_hist + (size_t)10 * B_ * H_
                                 : dec_hist + (size_t)(t - 1) * B_ * H_;
    gru_fused<false><<<dim3(8, 64), 256, 0, stream>>>(
        prev, whh_d, dec_bhh, xgb, nullptr, nullptr, nullptr, h,
        dec_hist + (size_t)t * B_ * H_);
  }

  // ---- Batched epilogue (ew3/a4 prescaled by LOG2E2 for out_seq) ----
  gemm_bf16<short><<<dim3(4, 320), 256, 0, stream>>>(
      enc_hist + (size_t)B_ * H_, H_, w3b, H_, nullptr, ew3, W_, H_, LOG2E2);
  gemm_bf16<short><<<dim3(4, 320), 256, 0, stream>>>(
      dec_hist, H_, w4b, H_, nullptr, a4, W_, H_, LOG2E2);
  out_seq_all<<<B_, 256, 0, stream>>>(ew3, a4, v2, out);
  out_ori_all<<<(B_ * L_) / 4, 256, 0, stream>>>(dec_hist, wori, bori, out);
}